// Round 5
// baseline (1687.909 us; speedup 1.0000x reference)
//
#include <hip/hip_runtime.h>

#define Bc 4
#define Tc 500
#define Uc 100
#define Vc 64
#define G4 2048

__device__ __forceinline__ float fsig(float x) {
  return __builtin_amdgcn_rcpf(1.f + __expf(-x));
}
__device__ __forceinline__ float ftanh(float x) {
  float e = __expf(2.f * x);
  return 1.f - 2.f * __builtin_amdgcn_rcpf(e + 1.f);
}

__device__ __forceinline__ unsigned ldA(const unsigned* p) {
  return __hip_atomic_load(p, __ATOMIC_RELAXED, __HIP_MEMORY_SCOPE_AGENT);
}
__device__ __forceinline__ void stA(unsigned* p, unsigned v) {
  __hip_atomic_store(p, v, __ATOMIC_RELAXED, __HIP_MEMORY_SCOPE_AGENT);
}
__device__ __forceinline__ void ctrBump(int* c) {
  __hip_atomic_fetch_add(c, 1, __ATOMIC_RELAXED, __HIP_MEMORY_SCOPE_AGENT);
}

// ---------------- generic GEMM tile ----------------
// C[n][m] = sum_k Arow(n)[k] * Bw[m*ldb + k] (+bias+bias2), K=512.
// ids != null: row n = emb[ids[n]]. Optional completion counter (agent).
template <int ATOMICST>
__device__ __forceinline__ void gemm_tile(
    const float* __restrict__ A, int lda,
    const float* __restrict__ Bw, int ldb,
    const float* __restrict__ bias, const float* __restrict__ bias2,
    float* __restrict__ C, int ldc, int N, int m0, int n0,
    const int* __restrict__ ids, const float* __restrict__ emb,
    int* __restrict__ ctr)
{
  __shared__ float As[16][65];
  __shared__ float Bs[16][65];
  const int tid = threadIdx.x;
  const int tx = tid & 15, ty = tid >> 4;
  float acc[4][4] = {};
  for (int k0 = 0; k0 < 512; k0 += 16) {
#pragma unroll
    for (int i = 0; i < 4; ++i) {
      int n = n0 + ty + 16 * i;
      float av = 0.f;
      if (n < N) {
        const float* ar = ids ? (emb + (long)ids[n] * 512) : (A + (long)n * lda);
        av = ar[k0 + tx];
      }
      As[tx][ty + 16 * i] = av;
      Bs[tx][ty + 16 * i] = Bw[(long)(m0 + ty + 16 * i) * ldb + k0 + tx];
    }
    __syncthreads();
#pragma unroll
    for (int kl = 0; kl < 16; ++kl) {
      float a[4], b[4];
#pragma unroll
      for (int i = 0; i < 4; ++i) a[i] = As[kl][ty * 4 + i];
#pragma unroll
      for (int j = 0; j < 4; ++j) b[j] = Bs[kl][tx * 4 + j];
#pragma unroll
      for (int i = 0; i < 4; ++i)
#pragma unroll
        for (int j = 0; j < 4; ++j) acc[i][j] += a[i] * b[j];
    }
    __syncthreads();
  }
#pragma unroll
  for (int i = 0; i < 4; ++i) {
    int n = n0 + ty * 4 + i;
    if (n >= N) continue;
#pragma unroll
    for (int j = 0; j < 4; ++j) {
      int m = m0 + tx * 4 + j;
      float v = acc[i][j];
      if (bias)  v += bias[m];
      if (bias2) v += bias2[m];
      if (ATOMICST)
        stA((unsigned*)C + (long)n * ldc + m, __float_as_uint(v));
      else
        C[(long)n * ldc + m] = v;
    }
  }
  if (ctr) {
    __syncthreads();          // drains stores (vmcnt) before counter publish
    if (tid == 0) ctrBump(ctr);
  }
}

// ---------------- wdc tile: wdc[h][e] = sum_d wd[h][d]*fc_w[d][e] ----------------
__device__ void wdc_tile(const float* __restrict__ jw1,
                         const float* __restrict__ fc_w,
                         float* __restrict__ wdc, int n0, int m0)
{
  __shared__ float As[16][65];
  __shared__ float Bs[16][65];
  const int tid = threadIdx.x;
  const int tx = tid & 15, ty = tid >> 4;
  float acc[4][4] = {};
  for (int k0 = 0; k0 < 512; k0 += 16) {
#pragma unroll
    for (int i = 0; i < 4; ++i) {
      As[tx][ty + 16 * i] = jw1[(long)(n0 + ty + 16 * i) * 1024 + 512 + k0 + tx];
      Bs[ty][tx + 16 * i] = fc_w[(long)(k0 + ty) * 512 + m0 + tx + 16 * i];
    }
    __syncthreads();
#pragma unroll
    for (int kl = 0; kl < 16; ++kl) {
      float a[4], b[4];
#pragma unroll
      for (int i = 0; i < 4; ++i) a[i] = As[kl][ty * 4 + i];
#pragma unroll
      for (int j = 0; j < 4; ++j) b[j] = Bs[kl][tx * 4 + j];
#pragma unroll
      for (int i = 0; i < 4; ++i)
#pragma unroll
        for (int j = 0; j < 4; ++j) acc[i][j] += a[i] * b[j];
    }
    __syncthreads();
  }
#pragma unroll
  for (int i = 0; i < 4; ++i)
#pragma unroll
    for (int j = 0; j < 4; ++j)
      stA((unsigned*)wdc + (long)(n0 + ty * 4 + i) * 512 + m0 + tx * 4 + j,
          __float_as_uint(acc[i][j]));
}

// ---------------- dec tile (flag-gated, ldA + NaN backstop) ----------------
// dec[n][h] = sum_e h1s(row n)[e] * wdc[h][e] + bdc[h]; n=(b,u), N=400.
__device__ void dec_tile(const float* __restrict__ h1s, const float* __restrict__ wdc,
                         const float* __restrict__ jw1, const float* __restrict__ fc_b,
                         const float* __restrict__ jb1, float* __restrict__ decb,
                         const int* __restrict__ f1, int* __restrict__ dctr,
                         int m0, int n0)
{
  __shared__ float As[16][65];
  __shared__ float Bs[16][65];
  __shared__ float biasl[64];
  const int tid = threadIdx.x;
  const int tx = tid & 15, ty = tid >> 4;
  int u_hi = 0;
  for (int rr = 0; rr < 64; ++rr) {
    int r = n0 + rr;
    if (r < 400) { int u = r % Uc; u_hi = max(u_hi, u + 1); }
  }
  if (tid < 64)
    while ((int)ldA((const unsigned*)(f1 + tid * 16)) < u_hi)
      __builtin_amdgcn_s_sleep(8);
  if (tid < 64) {
    int m = m0 + tid;
    const float4* wp = (const float4*)(jw1 + (long)m * 1024 + 512);
    const float4* fb = (const float4*)fc_b;
    float bb = jb1[m];
#pragma unroll 8
    for (int d4 = 0; d4 < 128; ++d4) {
      float4 w = wp[d4], f = fb[d4];
      bb += w.x * f.x + w.y * f.y + w.z * f.z + w.w * f.w;
    }
    biasl[tid] = bb;
  }
  __syncthreads();
  const unsigned* h1u = (const unsigned*)h1s;
  const unsigned* wdu = (const unsigned*)wdc;
  float acc[4][4] = {};
  for (int k0 = 0; k0 < 512; k0 += 16) {
    unsigned uA[4], uB[4];
#pragma unroll
    for (int i = 0; i < 4; ++i) {
      int n = n0 + ty + 16 * i;
      uA[i] = (n < 400) ? ldA(h1u + (long)(n % Uc) * G4 + (n / Uc) * 512 + k0 + tx) : 0u;
      uB[i] = ldA(wdu + (long)(m0 + ty + 16 * i) * 512 + k0 + tx);
    }
#pragma unroll
    for (int i = 0; i < 4; ++i) {
      int n = n0 + ty + 16 * i;
      while (uA[i] == 0xFFFFFFFFu)
        uA[i] = ldA(h1u + (long)(n % Uc) * G4 + (n / Uc) * 512 + k0 + tx);
      while (uB[i] == 0xFFFFFFFFu)
        uB[i] = ldA(wdu + (long)(m0 + ty + 16 * i) * 512 + k0 + tx);
      As[tx][ty + 16 * i] = __uint_as_float(uA[i]);
      Bs[tx][ty + 16 * i] = __uint_as_float(uB[i]);
    }
    __syncthreads();
#pragma unroll
    for (int kl = 0; kl < 16; ++kl) {
      float a[4], b[4];
#pragma unroll
      for (int i = 0; i < 4; ++i) a[i] = As[kl][ty * 4 + i];
#pragma unroll
      for (int j = 0; j < 4; ++j) b[j] = Bs[kl][tx * 4 + j];
#pragma unroll
      for (int i = 0; i < 4; ++i)
#pragma unroll
        for (int j = 0; j < 4; ++j) acc[i][j] += a[i] * b[j];
    }
    __syncthreads();
  }
#pragma unroll
  for (int i = 0; i < 4; ++i) {
    int n = n0 + ty * 4 + i;
    if (n >= 400) continue;
#pragma unroll
    for (int j = 0; j < 4; ++j)
      stA((unsigned*)decb + (long)n * 512 + m0 + tx * 4 + j,
          __float_as_uint(acc[i][j] + biasl[tx * 4 + j]));
  }
  __syncthreads();            // drain dec stores
  if (tid == 0) ctrBump(dctr);
}

// ---------------- joint tile (counter-gated, streams inside k_fused) ----------------
// out[n][v] = sum_h tanh(enc[n/100][h] + dec[b*100+u][h]) * jw2[v][h] + jb2[v]
__device__ void joint_tile(const float* __restrict__ enc, const float* __restrict__ dec,
                           const float* __restrict__ jw2, const float* __restrict__ jb2,
                           float* __restrict__ out,
                           const int* __restrict__ enc_ctr,
                           const int* __restrict__ dec_ctr, int n0)
{
  __shared__ float As[16][65];
  __shared__ float Bs[16][65];
  const int tid = threadIdx.x;
  const int tx = tid & 15, ty = tid >> 4;
  // gate: enc row-groups (<=2) and dec row-groups (<=7) complete
  if (tid == 0) {
    int g0 = (n0 / Uc) >> 6, g1 = ((n0 + 63) / Uc) >> 6;
    for (int g = g0; g <= g1; ++g)
      while ((int)ldA((const unsigned*)(enc_ctr + g * 16)) < 8)
        __builtin_amdgcn_s_sleep(16);
  }
  if (tid == 64) {
    unsigned mask = 0;
    for (int rr = 0; rr < 64; ++rr) {
      int n = n0 + rr;
      mask |= 1u << ((n / (Tc * Uc) * Uc + n % Uc) >> 6);
    }
    for (int g = 0; g < 7; ++g)
      if ((mask >> g) & 1)
        while ((int)ldA((const unsigned*)(dec_ctr + g * 16)) < 8)
          __builtin_amdgcn_s_sleep(16);
  }
  __syncthreads();
  const unsigned* eu = (const unsigned*)enc;
  const unsigned* du = (const unsigned*)dec;
  long eoff[4], doff[4];
#pragma unroll
  for (int i = 0; i < 4; ++i) {
    int n = n0 + ty + 16 * i;
    eoff[i] = (long)(n / Uc) * 512;
    doff[i] = (long)(n / (Tc * Uc) * Uc + n % Uc) * 512;
  }
  float acc[4][4] = {};
  for (int k0 = 0; k0 < 512; k0 += 16) {
#pragma unroll
    for (int i = 0; i < 4; ++i) {
      unsigned ue = ldA(eu + eoff[i] + k0 + tx);
      unsigned ud = ldA(du + doff[i] + k0 + tx);
      while (ue == 0xFFFFFFFFu) ue = ldA(eu + eoff[i] + k0 + tx);
      while (ud == 0xFFFFFFFFu) ud = ldA(du + doff[i] + k0 + tx);
      As[tx][ty + 16 * i] = ftanh(__uint_as_float(ue) + __uint_as_float(ud));
      Bs[tx][ty + 16 * i] = jw2[(long)(ty + 16 * i) * 512 + k0 + tx];
    }
    __syncthreads();
#pragma unroll
    for (int kl = 0; kl < 16; ++kl) {
      float a[4], b[4];
#pragma unroll
      for (int i = 0; i < 4; ++i) a[i] = As[kl][ty * 4 + i];
#pragma unroll
      for (int j = 0; j < 4; ++j) b[j] = Bs[kl][tx * 4 + j];
#pragma unroll
      for (int i = 0; i < 4; ++i)
#pragma unroll
        for (int j = 0; j < 4; ++j) acc[i][j] += a[i] * b[j];
    }
    __syncthreads();
  }
#pragma unroll
  for (int i = 0; i < 4; ++i) {
    long n = n0 + ty * 4 + i;
#pragma unroll
    for (int j = 0; j < 4; ++j)
      out[n * 64 + tx * 4 + j] = acc[i][j] + jb2[tx * 4 + j];
  }
}

// ---------------- dataflow LSTM recurrence (unchanged from r4) ----------------
__device__ void rec_path(
    const float* __restrict__ ixp0,
    const float* __restrict__ wih1, const float* __restrict__ whh0,
    const float* __restrict__ whh1,
    const float* __restrict__ bih1, const float* __restrict__ bhh1,
    float* __restrict__ h0s, float* __restrict__ h1s,
    float* __restrict__ hO, float* __restrict__ cO, int* __restrict__ flags)
{
  __shared__ float4 hl4[1024];
  __shared__ float4 red4[256];
  const int tid = threadIdx.x;
  const int blk = blockIdx.x;
  const bool isL1 = blk >= 32;
  const int rg = tid & 15, ks = tid >> 4;
  const int lane = tid & 63, wv = tid >> 6;
  const int* f0 = flags;
  const int* f1 = flags + 512;
  unsigned* myflag = (unsigned*)(isL1 ? (f1 + (blk - 32) * 16) : (f0 + blk * 16));

  float4 wr4[4][8];
#pragma unroll
  for (int r = 0; r < 4; ++r) {
    int lr = rg * 4 + r;
    const float* wsrc; int grow;
    if (!isL1) { int q = lr >> 4, uu = lr & 15; grow = q * 512 + blk * 16 + uu; wsrc = whh0; }
    else {
      int jb = blk - 32; int half = lr >> 5, q = (lr >> 3) & 3, uu = lr & 7;
      grow = q * 512 + jb * 8 + uu; wsrc = half ? whh1 : wih1;
    }
    const float4* wp = (const float4*)(wsrc + (long)grow * 512 + ks * 32);
#pragma unroll
    for (int jj = 0; jj < 8; ++jj) wr4[r][jj] = wp[jj];
  }

  const int nu = isL1 ? 8 : 16;
  const bool eact = tid < nu * 4;
  const int euu = tid >> 2, eb = tid & 3;
  float creg = 0.f;
  float bgate[4] = {0.f, 0.f, 0.f, 0.f};
  if (isL1 && eact) {
#pragma unroll
    for (int q = 0; q < 4; ++q) {
      int grow = q * 512 + (blk - 32) * 8 + euu;
      bgate[q] = bih1[grow] + bhh1[grow];
    }
  }

  const unsigned* h0u = (const unsigned*)h0s;
  const unsigned* h1u = (const unsigned*)h1s;
  const unsigned* ixu = (const unsigned*)ixp0;
  const int hsrc = (isL1 && rg >= 8) ? 1 : 0;
  const float* redf = (const float*)red4;

  for (int s = 0; s < Uc; ++s) {
    float ixv[4] = {0.f, 0.f, 0.f, 0.f};
    if (wv == 0) {
      if (!isL1 && eact) {
        const unsigned* ib = ixu + ((long)(eb * Uc + s) * G4 + blk * 16 + euu);
        unsigned g0, g1, g2, g3;
        while (true) {
          g0 = ldA(ib); g1 = ldA(ib + 512); g2 = ldA(ib + 1024); g3 = ldA(ib + 1536);
          if (g0 != 0xFFFFFFFFu && g1 != 0xFFFFFFFFu &&
              g2 != 0xFFFFFFFFu && g3 != 0xFFFFFFFFu) break;
          __builtin_amdgcn_s_sleep(1);
        }
        ixv[0] = __uint_as_float(g0); ixv[1] = __uint_as_float(g1);
        ixv[2] = __uint_as_float(g2); ixv[3] = __uint_as_float(g3);
      }
      if (!isL1) {
        if (s > 0 && lane < 32)
          while ((int)ldA((const unsigned*)(f0 + lane * 16)) < s)
            __builtin_amdgcn_s_sleep(2);
      } else {
        if (lane < 32)
          while ((int)ldA((const unsigned*)(f0 + lane * 16)) < s + 1)
            __builtin_amdgcn_s_sleep(2);
        if (s > 0)
          while ((int)ldA((const unsigned*)(f1 + lane * 16)) < s)
            __builtin_amdgcn_s_sleep(2);
      }
    }
    __syncthreads();

    unsigned ha[8], hb[8];
    {
      const unsigned* pa = nullptr; const unsigned* pb = nullptr;
      if (!isL1) { if (s > 0) pa = h0u + (long)(s - 1) * G4 + tid * 4; }
      else {
        pa = h0u + (long)s * G4 + tid * 4;
        if (s > 0) pb = h1u + (long)(s - 1) * G4 + tid * 4;
      }
      bool done = false;
      while (!done) {
        bool ok = true;
        if (pa) {
#pragma unroll
          for (int it = 0; it < 2; ++it)
#pragma unroll
            for (int c = 0; c < 4; ++c) {
              unsigned u = ldA(pa + it * 1024 + c);
              ha[it * 4 + c] = u; ok &= (u != 0xFFFFFFFFu);
            }
        }
        if (pb) {
#pragma unroll
          for (int it = 0; it < 2; ++it)
#pragma unroll
            for (int c = 0; c < 4; ++c) {
              unsigned u = ldA(pb + it * 1024 + c);
              hb[it * 4 + c] = u; ok &= (u != 0xFFFFFFFFu);
            }
        }
        done = ok;
        if (!done) __builtin_amdgcn_s_sleep(1);
      }
      if (!pa) { for (int i = 0; i < 8; ++i) ha[i] = 0u; }
      if (!pb) { for (int i = 0; i < 8; ++i) hb[i] = 0u; }
    }
#pragma unroll
    for (int it = 0; it < 2; ++it) {
      int qd = tid + it * 256;
      int b = qd >> 7, kq = qd & 127;
      int c = kq >> 3, o = kq & 7;
      int dst = b * 128 + c * 8 + ((o + c) & 7);
      hl4[dst] = make_float4(__uint_as_float(ha[it * 4 + 0]), __uint_as_float(ha[it * 4 + 1]),
                             __uint_as_float(ha[it * 4 + 2]), __uint_as_float(ha[it * 4 + 3]));
      if (isL1)
        hl4[512 + dst] = make_float4(__uint_as_float(hb[it * 4 + 0]), __uint_as_float(hb[it * 4 + 1]),
                                     __uint_as_float(hb[it * 4 + 2]), __uint_as_float(hb[it * 4 + 3]));
    }
    __syncthreads();

    float acc[4][4] = {};
#pragma unroll
    for (int j = 0; j < 8; ++j) {
      int pq = hsrc * 512 + ks * 8 + ((j + ks) & 7);
      float4 h0q = hl4[pq];
      float4 h1q = hl4[pq + 128];
      float4 h2q = hl4[pq + 256];
      float4 h3q = hl4[pq + 384];
#pragma unroll
      for (int r = 0; r < 4; ++r) {
        float4 w = wr4[r][j];
        acc[r][0] += w.x * h0q.x + w.y * h0q.y + w.z * h0q.z + w.w * h0q.w;
        acc[r][1] += w.x * h1q.x + w.y * h1q.y + w.z * h1q.z + w.w * h1q.w;
        acc[r][2] += w.x * h2q.x + w.y * h2q.y + w.z * h2q.z + w.w * h2q.w;
        acc[r][3] += w.x * h3q.x + w.y * h3q.y + w.z * h3q.z + w.w * h3q.w;
      }
    }
#pragma unroll
    for (int r = 0; r < 4; ++r)
#pragma unroll
      for (int b = 0; b < 4; ++b) {
        float v = acc[r][b];
        v += __shfl_xor(v, 16);
        v += __shfl_xor(v, 32);
        acc[r][b] = v;
      }
    if (lane < 16) {
#pragma unroll
      for (int r = 0; r < 4; ++r)
        red4[wv * 64 + lane * 4 + r] =
            make_float4(acc[r][0], acc[r][1], acc[r][2], acc[r][3]);
    }
    __syncthreads();

    if (eact) {
      float gv[4];
#pragma unroll
      for (int q = 0; q < 4; ++q) {
        float sv = 0.f;
        int lrA = isL1 ? (q * 8 + euu) : (q * 16 + euu);
#pragma unroll
        for (int w = 0; w < 4; ++w) sv += redf[(w * 64 + lrA) * 4 + eb];
        if (isL1) {
          int lrB = 32 + q * 8 + euu;
#pragma unroll
          for (int w = 0; w < 4; ++w) sv += redf[(w * 64 + lrB) * 4 + eb];
          sv += bgate[q];
        } else {
          sv += ixv[q];
        }
        gv[q] = sv;
      }
      float cn = fsig(gv[1]) * creg + fsig(gv[0]) * ftanh(gv[2]);
      float hn = fsig(gv[3]) * ftanh(cn);
      creg = cn;
      int gu = (isL1 ? (blk - 32) * 8 : blk * 16) + euu;
      unsigned* dst = (unsigned*)(isL1 ? h1s : h0s) + (long)s * G4 + eb * 512 + gu;
      stA(dst, __float_as_uint(hn));
      if (s == Uc - 1) {
        hO[(isL1 ? G4 : 0) + eb * 512 + gu] = hn;
        cO[(isL1 ? G4 : 0) + eb * 512 + gu] = cn;
      }
    }
    __syncthreads();
    if (tid == 0) stA(myflag, (unsigned)(s + 1));
  }
}

// ---------------- fused launch ----------------
// 0..95 rec | 96..319 ixp | 320..383 wdc | 384..639 enc | 640..695 dec | 696..3820 joint
__global__ __launch_bounds__(256, 1) void k_fused(
    const int* __restrict__ ids, const float* __restrict__ emb,
    const float* __restrict__ memory,
    const float* __restrict__ w_ih, const float* __restrict__ b_ih,
    const float* __restrict__ b_hh,
    const float* __restrict__ wih1, const float* __restrict__ whh0,
    const float* __restrict__ whh1,
    const float* __restrict__ bih1, const float* __restrict__ bhh1,
    const float* __restrict__ jw1, const float* __restrict__ jb1,
    const float* __restrict__ fc_w, const float* __restrict__ fc_b,
    const float* __restrict__ jw2, const float* __restrict__ jb2,
    float* __restrict__ ixp0, float* __restrict__ h0s, float* __restrict__ h1s,
    float* __restrict__ wdc, float* __restrict__ decb, float* __restrict__ encb,
    float* __restrict__ out,
    float* __restrict__ hO, float* __restrict__ cO, int* __restrict__ flags)
{
  const int blk = blockIdx.x;
  int* dec_ctr = flags + 1536;   // 7 groups x 16 stride
  int* enc_ctr = flags + 2048;   // 32 groups x 16 stride
  if (blk < 96) {
    rec_path(ixp0, wih1, whh0, whh1, bih1, bhh1, h0s, h1s, hO, cO, flags);
  } else if (blk < 320) {
    static const int nt_ord[7] = {0, 1, 3, 4, 2, 5, 6};
    int g = blk - 96;
    gemm_tile<1>(nullptr, 0, w_ih, 512, b_ih, b_hh,
                 ixp0, G4, Bc * Uc, (g % 32) * 64, nt_ord[g / 32] * 64, ids, emb,
                 nullptr);
  } else if (blk < 384) {
    int g = blk - 320;
    wdc_tile(jw1, fc_w, wdc, (g & 7) * 64, (g >> 3) * 64);
  } else if (blk < 640) {
    int g = blk - 384;
    gemm_tile<1>(memory, 512, jw1, 1024, nullptr, nullptr,
                 encb, 512, Bc * Tc, (g & 7) * 64, (g >> 3) * 64, nullptr, nullptr,
                 enc_ctr + (g >> 3) * 16);
  } else if (blk < 696) {
    int g = blk - 640;
    dec_tile(h1s, wdc, jw1, fc_b, jb1, decb, flags + 512,
             dec_ctr + (g >> 3) * 16, (g & 7) * 64, (g >> 3) * 64);
  } else {
    joint_tile(encb, decb, jw2, jb2, out, enc_ctr, dec_ctr, (blk - 696) * 64);
  }
}

extern "C" void kernel_launch(void* const* d_in, const int* in_sizes, int n_in,
                              void* d_out, int out_size, void* d_ws, size_t ws_size,
                              hipStream_t stream)
{
  const int*   ids    = (const int*)d_in[0];
  const float* memory = (const float*)d_in[1];
  const float* emb    = (const float*)d_in[2];
  const float* w_ih   = (const float*)d_in[3];
  const float* w_hh   = (const float*)d_in[4];
  const float* b_ih   = (const float*)d_in[5];
  const float* b_hh   = (const float*)d_in[6];
  const float* fc_w   = (const float*)d_in[7];
  const float* fc_b   = (const float*)d_in[8];
  const float* jw1    = (const float*)d_in[9];
  const float* jb1    = (const float*)d_in[10];
  const float* jw2    = (const float*)d_in[11];
  const float* jb2    = (const float*)d_in[12];
  float* out = (float*)d_out;

  float* wsf = (float*)d_ws;
  int*   flags = (int*)d_ws;                 // 4096 ints: f0|f1|dec_ctr|enc_ctr
  float* ixp0  = wsf + 4096;                 // 819200
  float* h0s   = wsf + 823296;               // 204800
  float* h1s   = wsf + 1028096;              // 204800
  float* wdc   = wsf + 1232896;              // 262144
  float* decb  = wsf + 1495040;              // 204800
  float* encb  = wsf + 1699840;              // 1024000  (end 2723840 floats ~10.9MB)

  float* hO = out + (long)Bc * Tc * Uc * Vc;
  float* cO = hO + 2 * Bc * 512;

  // flags/counters = 0; NaN-init ALL dataflow regions (ixp0,h0s,h1s,wdc,decb,encb)
  hipMemsetAsync(flags, 0, 4096 * 4, stream);
  hipMemsetAsync(ixp0, 0xFF, (size_t)(2723840 - 4096) * 4, stream);

  k_fused<<<3821, 256, 0, stream>>>(ids, emb, memory,
                                    w_ih, b_ih, b_hh,
                                    w_ih + (long)G4 * 512,  // wih1
                                    w_hh,                   // whh0
                                    w_hh + (long)G4 * 512,  // whh1
                                    b_ih + G4, b_hh + G4,
                                    jw1, jb1, fc_w, fc_b, jw2, jb2,
                                    ixp0, h0s, h1s, wdc, decb, encb,
                                    out, hO, cO, flags);
}

// Round 6
// 986.363 us; speedup vs baseline: 1.7112x; 1.7112x over previous
//
#include <hip/hip_runtime.h>

#define Bc 4
#define Tc 500
#define Uc 100
#define Vc 64
#define G4 2048

typedef __attribute__((ext_vector_type(8))) short short8v;
typedef __attribute__((ext_vector_type(4))) float f32x4;

__device__ __forceinline__ float fsig(float x) {
  return __builtin_amdgcn_rcpf(1.f + __expf(-x));
}
__device__ __forceinline__ float ftanh(float x) {
  float e = __expf(2.f * x);
  return 1.f - 2.f * __builtin_amdgcn_rcpf(e + 1.f);
}
__device__ __forceinline__ short f2bf(float f) {
  unsigned u = __float_as_uint(f);
  unsigned r = (u + 0x7FFFu + ((u >> 16) & 1u)) >> 16;
  return (short)r;
}

__device__ __forceinline__ unsigned ldA(const unsigned* p) {
  return __hip_atomic_load(p, __ATOMIC_RELAXED, __HIP_MEMORY_SCOPE_AGENT);
}
__device__ __forceinline__ void stA(unsigned* p, unsigned v) {
  __hip_atomic_store(p, v, __ATOMIC_RELAXED, __HIP_MEMORY_SCOPE_AGENT);
}
__device__ __forceinline__ void ctrBump(int* c) {
  __hip_atomic_fetch_add(c, 1, __ATOMIC_RELAXED, __HIP_MEMORY_SCOPE_AGENT);
}

// ---------------- generic GEMM tile ----------------
template <int ATOMICST>
__device__ __forceinline__ void gemm_tile(
    const float* __restrict__ A, int lda,
    const float* __restrict__ Bw, int ldb,
    const float* __restrict__ bias, const float* __restrict__ bias2,
    float* __restrict__ C, int ldc, int N, int m0, int n0,
    const int* __restrict__ ids, const float* __restrict__ emb,
    int* __restrict__ ctr)
{
  __shared__ float As[16][65];
  __shared__ float Bs[16][65];
  const int tid = threadIdx.x;
  const int tx = tid & 15, ty = tid >> 4;
  float acc[4][4] = {};
  for (int k0 = 0; k0 < 512; k0 += 16) {
#pragma unroll
    for (int i = 0; i < 4; ++i) {
      int n = n0 + ty + 16 * i;
      float av = 0.f;
      if (n < N) {
        const float* ar = ids ? (emb + (long)ids[n] * 512) : (A + (long)n * lda);
        av = ar[k0 + tx];
      }
      As[tx][ty + 16 * i] = av;
      Bs[tx][ty + 16 * i] = Bw[(long)(m0 + ty + 16 * i) * ldb + k0 + tx];
    }
    __syncthreads();
#pragma unroll
    for (int kl = 0; kl < 16; ++kl) {
      float a[4], b[4];
#pragma unroll
      for (int i = 0; i < 4; ++i) a[i] = As[kl][ty * 4 + i];
#pragma unroll
      for (int j = 0; j < 4; ++j) b[j] = Bs[kl][tx * 4 + j];
#pragma unroll
      for (int i = 0; i < 4; ++i)
#pragma unroll
        for (int j = 0; j < 4; ++j) acc[i][j] += a[i] * b[j];
    }
    __syncthreads();
  }
#pragma unroll
  for (int i = 0; i < 4; ++i) {
    int n = n0 + ty * 4 + i;
    if (n >= N) continue;
#pragma unroll
    for (int j = 0; j < 4; ++j) {
      int m = m0 + tx * 4 + j;
      float v = acc[i][j];
      if (bias)  v += bias[m];
      if (bias2) v += bias2[m];
      if (ATOMICST)
        stA((unsigned*)C + (long)n * ldc + m, __float_as_uint(v));
      else
        C[(long)n * ldc + m] = v;
    }
  }
  if (ctr) {
    __syncthreads();
    if (tid == 0) ctrBump(ctr);
  }
}

// ---------------- wdc tile: wdc[h][e] = sum_d wd[h][d]*fc_w[d][e] ----------------
__device__ void wdc_tile(const float* __restrict__ jw1,
                         const float* __restrict__ fc_w,
                         float* __restrict__ wdc, int n0, int m0)
{
  __shared__ float As[16][65];
  __shared__ float Bs[16][65];
  const int tid = threadIdx.x;
  const int tx = tid & 15, ty = tid >> 4;
  float acc[4][4] = {};
  for (int k0 = 0; k0 < 512; k0 += 16) {
#pragma unroll
    for (int i = 0; i < 4; ++i) {
      As[tx][ty + 16 * i] = jw1[(long)(n0 + ty + 16 * i) * 1024 + 512 + k0 + tx];
      Bs[ty][tx + 16 * i] = fc_w[(long)(k0 + ty) * 512 + m0 + tx + 16 * i];
    }
    __syncthreads();
#pragma unroll
    for (int kl = 0; kl < 16; ++kl) {
      float a[4], b[4];
#pragma unroll
      for (int i = 0; i < 4; ++i) a[i] = As[kl][ty * 4 + i];
#pragma unroll
      for (int j = 0; j < 4; ++j) b[j] = Bs[kl][tx * 4 + j];
#pragma unroll
      for (int i = 0; i < 4; ++i)
#pragma unroll
        for (int j = 0; j < 4; ++j) acc[i][j] += a[i] * b[j];
    }
    __syncthreads();
  }
#pragma unroll
  for (int i = 0; i < 4; ++i)
#pragma unroll
    for (int j = 0; j < 4; ++j)
      stA((unsigned*)wdc + (long)(n0 + ty * 4 + i) * 512 + m0 + tx * 4 + j,
          __float_as_uint(acc[i][j]));
}

// ---------------- dec tile (flag-gated, ldA + NaN backstop) ----------------
__device__ void dec_tile(const float* __restrict__ h1s, const float* __restrict__ wdc,
                         const float* __restrict__ jw1, const float* __restrict__ fc_b,
                         const float* __restrict__ jb1, float* __restrict__ decb,
                         const int* __restrict__ f1, int m0, int n0)
{
  __shared__ float As[16][65];
  __shared__ float Bs[16][65];
  __shared__ float biasl[64];
  const int tid = threadIdx.x;
  const int tx = tid & 15, ty = tid >> 4;
  int u_hi = 0;
  for (int rr = 0; rr < 64; ++rr) {
    int r = n0 + rr;
    if (r < 400) { int u = r % Uc; u_hi = max(u_hi, u + 1); }
  }
  if (tid < 64)
    while ((int)ldA((const unsigned*)(f1 + tid * 16)) < u_hi)
      __builtin_amdgcn_s_sleep(8);
  if (tid < 64) {
    int m = m0 + tid;
    const float4* wp = (const float4*)(jw1 + (long)m * 1024 + 512);
    const float4* fb = (const float4*)fc_b;
    float bb = jb1[m];
#pragma unroll 8
    for (int d4 = 0; d4 < 128; ++d4) {
      float4 w = wp[d4], f = fb[d4];
      bb += w.x * f.x + w.y * f.y + w.z * f.z + w.w * f.w;
    }
    biasl[tid] = bb;
  }
  __syncthreads();
  const unsigned* h1u = (const unsigned*)h1s;
  const unsigned* wdu = (const unsigned*)wdc;
  float acc[4][4] = {};
  for (int k0 = 0; k0 < 512; k0 += 16) {
    unsigned uA[4], uB[4];
#pragma unroll
    for (int i = 0; i < 4; ++i) {
      int n = n0 + ty + 16 * i;
      uA[i] = (n < 400) ? ldA(h1u + (long)(n % Uc) * G4 + (n / Uc) * 512 + k0 + tx) : 0u;
      uB[i] = ldA(wdu + (long)(m0 + ty + 16 * i) * 512 + k0 + tx);
    }
#pragma unroll
    for (int i = 0; i < 4; ++i) {
      int n = n0 + ty + 16 * i;
      while (uA[i] == 0xFFFFFFFFu)
        uA[i] = ldA(h1u + (long)(n % Uc) * G4 + (n / Uc) * 512 + k0 + tx);
      while (uB[i] == 0xFFFFFFFFu)
        uB[i] = ldA(wdu + (long)(m0 + ty + 16 * i) * 512 + k0 + tx);
      As[tx][ty + 16 * i] = __uint_as_float(uA[i]);
      Bs[tx][ty + 16 * i] = __uint_as_float(uB[i]);
    }
    __syncthreads();
#pragma unroll
    for (int kl = 0; kl < 16; ++kl) {
      float a[4], b[4];
#pragma unroll
      for (int i = 0; i < 4; ++i) a[i] = As[kl][ty * 4 + i];
#pragma unroll
      for (int j = 0; j < 4; ++j) b[j] = Bs[kl][tx * 4 + j];
#pragma unroll
      for (int i = 0; i < 4; ++i)
#pragma unroll
        for (int j = 0; j < 4; ++j) acc[i][j] += a[i] * b[j];
    }
    __syncthreads();
  }
#pragma unroll
  for (int i = 0; i < 4; ++i) {
    int n = n0 + ty * 4 + i;
    if (n >= 400) continue;
#pragma unroll
    for (int j = 0; j < 4; ++j)
      stA((unsigned*)decb + (long)n * 512 + m0 + tx * 4 + j,
          __float_as_uint(acc[i][j] + biasl[tx * 4 + j]));
  }
}

// ---------------- dataflow LSTM recurrence (r3/r4-proven) ----------------
__device__ void rec_path(
    const float* __restrict__ ixp0,
    const float* __restrict__ wih1, const float* __restrict__ whh0,
    const float* __restrict__ whh1,
    const float* __restrict__ bih1, const float* __restrict__ bhh1,
    float* __restrict__ h0s, float* __restrict__ h1s,
    float* __restrict__ hO, float* __restrict__ cO, int* __restrict__ flags)
{
  __shared__ float4 hl4[1024];
  __shared__ float4 red4[256];
  const int tid = threadIdx.x;
  const int blk = blockIdx.x;
  const bool isL1 = blk >= 32;
  const int rg = tid & 15, ks = tid >> 4;
  const int lane = tid & 63, wv = tid >> 6;
  const int* f0 = flags;
  const int* f1 = flags + 512;
  unsigned* myflag = (unsigned*)(isL1 ? (f1 + (blk - 32) * 16) : (f0 + blk * 16));

  float4 wr4[4][8];
#pragma unroll
  for (int r = 0; r < 4; ++r) {
    int lr = rg * 4 + r;
    const float* wsrc; int grow;
    if (!isL1) { int q = lr >> 4, uu = lr & 15; grow = q * 512 + blk * 16 + uu; wsrc = whh0; }
    else {
      int jb = blk - 32; int half = lr >> 5, q = (lr >> 3) & 3, uu = lr & 7;
      grow = q * 512 + jb * 8 + uu; wsrc = half ? whh1 : wih1;
    }
    const float4* wp = (const float4*)(wsrc + (long)grow * 512 + ks * 32);
#pragma unroll
    for (int jj = 0; jj < 8; ++jj) wr4[r][jj] = wp[jj];
  }

  const int nu = isL1 ? 8 : 16;
  const bool eact = tid < nu * 4;
  const int euu = tid >> 2, eb = tid & 3;
  float creg = 0.f;
  float bgate[4] = {0.f, 0.f, 0.f, 0.f};
  if (isL1 && eact) {
#pragma unroll
    for (int q = 0; q < 4; ++q) {
      int grow = q * 512 + (blk - 32) * 8 + euu;
      bgate[q] = bih1[grow] + bhh1[grow];
    }
  }

  const unsigned* h0u = (const unsigned*)h0s;
  const unsigned* h1u = (const unsigned*)h1s;
  const unsigned* ixu = (const unsigned*)ixp0;
  const int hsrc = (isL1 && rg >= 8) ? 1 : 0;
  const float* redf = (const float*)red4;

  for (int s = 0; s < Uc; ++s) {
    float ixv[4] = {0.f, 0.f, 0.f, 0.f};
    if (wv == 0) {
      if (!isL1 && eact) {
        const unsigned* ib = ixu + ((long)(eb * Uc + s) * G4 + blk * 16 + euu);
        unsigned g0, g1, g2, g3;
        while (true) {
          g0 = ldA(ib); g1 = ldA(ib + 512); g2 = ldA(ib + 1024); g3 = ldA(ib + 1536);
          if (g0 != 0xFFFFFFFFu && g1 != 0xFFFFFFFFu &&
              g2 != 0xFFFFFFFFu && g3 != 0xFFFFFFFFu) break;
          __builtin_amdgcn_s_sleep(1);
        }
        ixv[0] = __uint_as_float(g0); ixv[1] = __uint_as_float(g1);
        ixv[2] = __uint_as_float(g2); ixv[3] = __uint_as_float(g3);
      }
      if (!isL1) {
        if (s > 0 && lane < 32)
          while ((int)ldA((const unsigned*)(f0 + lane * 16)) < s)
            __builtin_amdgcn_s_sleep(2);
      } else {
        if (lane < 32)
          while ((int)ldA((const unsigned*)(f0 + lane * 16)) < s + 1)
            __builtin_amdgcn_s_sleep(2);
        if (s > 0)
          while ((int)ldA((const unsigned*)(f1 + lane * 16)) < s)
            __builtin_amdgcn_s_sleep(2);
      }
    }
    __syncthreads();

    unsigned ha[8], hb[8];
    {
      const unsigned* pa = nullptr; const unsigned* pb = nullptr;
      if (!isL1) { if (s > 0) pa = h0u + (long)(s - 1) * G4 + tid * 4; }
      else {
        pa = h0u + (long)s * G4 + tid * 4;
        if (s > 0) pb = h1u + (long)(s - 1) * G4 + tid * 4;
      }
      bool done = false;
      while (!done) {
        bool ok = true;
        if (pa) {
#pragma unroll
          for (int it = 0; it < 2; ++it)
#pragma unroll
            for (int c = 0; c < 4; ++c) {
              unsigned u = ldA(pa + it * 1024 + c);
              ha[it * 4 + c] = u; ok &= (u != 0xFFFFFFFFu);
            }
        }
        if (pb) {
#pragma unroll
          for (int it = 0; it < 2; ++it)
#pragma unroll
            for (int c = 0; c < 4; ++c) {
              unsigned u = ldA(pb + it * 1024 + c);
              hb[it * 4 + c] = u; ok &= (u != 0xFFFFFFFFu);
            }
        }
        done = ok;
        if (!done) __builtin_amdgcn_s_sleep(1);
      }
      if (!pa) { for (int i = 0; i < 8; ++i) ha[i] = 0u; }
      if (!pb) { for (int i = 0; i < 8; ++i) hb[i] = 0u; }
    }
#pragma unroll
    for (int it = 0; it < 2; ++it) {
      int qd = tid + it * 256;
      int b = qd >> 7, kq = qd & 127;
      int c = kq >> 3, o = kq & 7;
      int dst = b * 128 + c * 8 + ((o + c) & 7);
      hl4[dst] = make_float4(__uint_as_float(ha[it * 4 + 0]), __uint_as_float(ha[it * 4 + 1]),
                             __uint_as_float(ha[it * 4 + 2]), __uint_as_float(ha[it * 4 + 3]));
      if (isL1)
        hl4[512 + dst] = make_float4(__uint_as_float(hb[it * 4 + 0]), __uint_as_float(hb[it * 4 + 1]),
                                     __uint_as_float(hb[it * 4 + 2]), __uint_as_float(hb[it * 4 + 3]));
    }
    __syncthreads();

    float acc[4][4] = {};
#pragma unroll
    for (int j = 0; j < 8; ++j) {
      int pq = hsrc * 512 + ks * 8 + ((j + ks) & 7);
      float4 h0q = hl4[pq];
      float4 h1q = hl4[pq + 128];
      float4 h2q = hl4[pq + 256];
      float4 h3q = hl4[pq + 384];
#pragma unroll
      for (int r = 0; r < 4; ++r) {
        float4 w = wr4[r][j];
        acc[r][0] += w.x * h0q.x + w.y * h0q.y + w.z * h0q.z + w.w * h0q.w;
        acc[r][1] += w.x * h1q.x + w.y * h1q.y + w.z * h1q.z + w.w * h1q.w;
        acc[r][2] += w.x * h2q.x + w.y * h2q.y + w.z * h2q.z + w.w * h2q.w;
        acc[r][3] += w.x * h3q.x + w.y * h3q.y + w.z * h3q.z + w.w * h3q.w;
      }
    }
#pragma unroll
    for (int r = 0; r < 4; ++r)
#pragma unroll
      for (int b = 0; b < 4; ++b) {
        float v = acc[r][b];
        v += __shfl_xor(v, 16);
        v += __shfl_xor(v, 32);
        acc[r][b] = v;
      }
    if (lane < 16) {
#pragma unroll
      for (int r = 0; r < 4; ++r)
        red4[wv * 64 + lane * 4 + r] =
            make_float4(acc[r][0], acc[r][1], acc[r][2], acc[r][3]);
    }
    __syncthreads();

    if (eact) {
      float gv[4];
#pragma unroll
      for (int q = 0; q < 4; ++q) {
        float sv = 0.f;
        int lrA = isL1 ? (q * 8 + euu) : (q * 16 + euu);
#pragma unroll
        for (int w = 0; w < 4; ++w) sv += redf[(w * 64 + lrA) * 4 + eb];
        if (isL1) {
          int lrB = 32 + q * 8 + euu;
#pragma unroll
          for (int w = 0; w < 4; ++w) sv += redf[(w * 64 + lrB) * 4 + eb];
          sv += bgate[q];
        } else {
          sv += ixv[q];
        }
        gv[q] = sv;
      }
      float cn = fsig(gv[1]) * creg + fsig(gv[0]) * ftanh(gv[2]);
      float hn = fsig(gv[3]) * ftanh(cn);
      creg = cn;
      int gu = (isL1 ? (blk - 32) * 8 : blk * 16) + euu;
      unsigned* dst = (unsigned*)(isL1 ? h1s : h0s) + (long)s * G4 + eb * 512 + gu;
      stA(dst, __float_as_uint(hn));
      if (s == Uc - 1) {
        hO[(isL1 ? G4 : 0) + eb * 512 + gu] = hn;
        cO[(isL1 ? G4 : 0) + eb * 512 + gu] = cn;
      }
    }
    __syncthreads();
    if (tid == 0) stA(myflag, (unsigned)(s + 1));
  }
}

// ---------------- fused launch (r4 structure) ----------------
// 0..95 rec | 96..319 ixp | 320..383 wdc | 384..639 enc | 640..695 dec
__global__ __launch_bounds__(256, 1) void k_fused(
    const int* __restrict__ ids, const float* __restrict__ emb,
    const float* __restrict__ memory,
    const float* __restrict__ w_ih, const float* __restrict__ b_ih,
    const float* __restrict__ b_hh,
    const float* __restrict__ wih1, const float* __restrict__ whh0,
    const float* __restrict__ whh1,
    const float* __restrict__ bih1, const float* __restrict__ bhh1,
    const float* __restrict__ jw1, const float* __restrict__ jb1,
    const float* __restrict__ fc_w, const float* __restrict__ fc_b,
    float* __restrict__ ixp0, float* __restrict__ h0s, float* __restrict__ h1s,
    float* __restrict__ wdc, float* __restrict__ decb, float* __restrict__ encb,
    float* __restrict__ hO, float* __restrict__ cO, int* __restrict__ flags)
{
  const int blk = blockIdx.x;
  if (blk < 96) {
    rec_path(ixp0, wih1, whh0, whh1, bih1, bhh1, h0s, h1s, hO, cO, flags);
  } else if (blk < 320) {
    static const int nt_ord[7] = {0, 1, 3, 4, 2, 5, 6};
    int g = blk - 96;
    gemm_tile<1>(nullptr, 0, w_ih, 512, b_ih, b_hh,
                 ixp0, G4, Bc * Uc, (g % 32) * 64, nt_ord[g / 32] * 64, ids, emb,
                 nullptr);
  } else if (blk < 384) {
    int g = blk - 320;
    wdc_tile(jw1, fc_w, wdc, (g & 7) * 64, (g >> 3) * 64);
  } else if (blk < 640) {
    int g = blk - 384;
    gemm_tile<0>(memory, 512, jw1, 1024, nullptr, nullptr,
                 encb, 512, Bc * Tc, (g & 7) * 64, (g >> 3) * 64, nullptr, nullptr,
                 nullptr);
  } else {
    int g = blk - 640;
    dec_tile(h1s, wdc, jw1, fc_b, jb1, decb, flags + 512, (g & 7) * 64, (g >> 3) * 64);
  }
}

// ---------------- joint via bf16 MFMA ----------------
// One block per (b,t). out[bt, u, v] = sum_k tanh(enc[bt][k]+dec[b,u][k])*jw2[v][k] + jb2[v]
// MFMA 16x16x32 bf16: A=th (u x k), B=jw2^T (k x v); per-wave v-strip of 16,
// 7 u-tiles (u padded 100->112). jw2 B-frags held in VGPRs (16 K-steps).
__global__ __launch_bounds__(256) void k_jmfma(
    const float* __restrict__ enc, const float* __restrict__ dec,
    const float* __restrict__ jw2, const float* __restrict__ jb2,
    float* __restrict__ out)
{
  __shared__ float el[512];
  __shared__ short th[112][136];   // bf16 tanh tile, K-chunk of 128 (+8 pad)
  const int tid = threadIdx.x;
  const int lane = tid & 63, wv = tid >> 6;
  const int bt = blockIdx.x;
  const int b = bt / Tc;
  const int v0 = wv * 16;
  const int vl = lane & 15, kg = lane >> 4;

  // B-frags: breg[ks][j] = bf16(jw2[v0+vl][ks*32 + kg*8 + j])
  short8v breg[16];
#pragma unroll
  for (int ksx = 0; ksx < 16; ++ksx) {
    const float* wp = jw2 + (long)(v0 + vl) * 512 + ksx * 32 + kg * 8;
    float4 x0 = *(const float4*)wp;
    float4 x1 = *(const float4*)(wp + 4);
    short8v t;
    t[0] = f2bf(x0.x); t[1] = f2bf(x0.y); t[2] = f2bf(x0.z); t[3] = f2bf(x0.w);
    t[4] = f2bf(x1.x); t[5] = f2bf(x1.y); t[6] = f2bf(x1.z); t[7] = f2bf(x1.w);
    breg[ksx] = t;
  }
  const float jbv = jb2[v0 + vl];
  for (int i = tid; i < 512; i += 256) el[i] = enc[(long)bt * 512 + i];

  f32x4 acc[7];
#pragma unroll
  for (int ut = 0; ut < 7; ++ut) acc[ut] = (f32x4){0.f, 0.f, 0.f, 0.f};
  __syncthreads();

  const float* dec0 = dec + (long)b * Uc * 512;
  for (int kc = 0; kc < 4; ++kc) {
    // tanh phase: th[u][kk] = bf16(tanh(el[kc*128+kk] + dec[u][kc*128+kk]))
#pragma unroll 5
    for (int it = 0; it < 50; ++it) {
      int flat = it * 256 + tid;           // 100*128 = 12800
      int u = flat >> 7, kk = flat & 127;
      float dv = dec0[(long)u * 512 + kc * 128 + kk];
      th[u][kk] = f2bf(ftanh(el[kc * 128 + kk] + dv));
    }
    __syncthreads();
#pragma unroll
    for (int ks4 = 0; ks4 < 4; ++ks4) {
      int ko = ks4 * 32 + kg * 8;
#pragma unroll
      for (int ut = 0; ut < 7; ++ut) {
        short8v a = *(const short8v*)&th[ut * 16 + vl][ko];
        acc[ut] = __builtin_amdgcn_mfma_f32_16x16x32_bf16(a, breg[kc * 4 + ks4],
                                                          acc[ut], 0, 0, 0);
      }
    }
    __syncthreads();
  }
  // epilogue: D row m=(lane>>4)*4+i (u-local), col n=lane&15 (v-local)
#pragma unroll
  for (int ut = 0; ut < 7; ++ut) {
#pragma unroll
    for (int i = 0; i < 4; ++i) {
      int u = ut * 16 + kg * 4 + i;
      if (u < Uc)
        out[((long)bt * Uc + u) * 64 + v0 + vl] = acc[ut][i] + jbv;
    }
  }
}

extern "C" void kernel_launch(void* const* d_in, const int* in_sizes, int n_in,
                              void* d_out, int out_size, void* d_ws, size_t ws_size,
                              hipStream_t stream)
{
  const int*   ids    = (const int*)d_in[0];
  const float* memory = (const float*)d_in[1];
  const float* emb    = (const float*)d_in[2];
  const float* w_ih   = (const float*)d_in[3];
  const float* w_hh   = (const float*)d_in[4];
  const float* b_ih   = (const float*)d_in[5];
  const float* b_hh   = (const float*)d_in[6];
  const float* fc_w   = (const float*)d_in[7];
  const float* fc_b   = (const float*)d_in[8];
  const float* jw1    = (const float*)d_in[9];
  const float* jb1    = (const float*)d_in[10];
  const float* jw2    = (const float*)d_in[11];
  const float* jb2    = (const float*)d_in[12];
  float* out = (float*)d_out;

  float* wsf = (float*)d_ws;
  int*   flags = (int*)d_ws;                 // 4096 ints
  float* ixp0  = wsf + 4096;                 // 819200
  float* h0s   = wsf + 823296;               // 204800
  float* h1s   = wsf + 1028096;              // 204800
  float* wdc   = wsf + 1232896;              // 262144
  float* decb  = wsf + 1495040;              // 204800
  float* encb  = wsf + 1699840;              // 1024000

  float* hO = out + (long)Bc * Tc * Uc * Vc;
  float* cO = hO + 2 * Bc * 512;

  // flags/counters = 0; NaN-init dataflow regions (ixp0,h0s,h1s,wdc,decb,encb)
  hipMemsetAsync(flags, 0, 4096 * 4, stream);
  hipMemsetAsync(ixp0, 0xFF, (size_t)(2723840 - 4096) * 4, stream);

  k_fused<<<696, 256, 0, stream>>>(ids, emb, memory,
                                   w_ih, b_ih, b_hh,
                                   w_ih + (long)G4 * 512,  // wih1
                                   w_hh,                   // whh0
                                   w_hh + (long)G4 * 512,  // whh1
                                   b_ih + G4, b_hh + G4,
                                   jw1, jb1, fc_w, fc_b,
                                   ixp0, h0s, h1s, wdc, decb, encb,
                                   hO, cO, flags);

  k_jmfma<<<2000, 256, 0, stream>>>(encb, decb, jw2, jb2, out);
}